// Round 1
// baseline (633.132 us; speedup 1.0000x reference)
//
#include <hip/hip_runtime.h>

#define EMB_D 128

// Pass 1: claim needed nodes. map[node] = slot+1 for some slot in [0, 2B).
__global__ void claim_kernel(const int* __restrict__ user_idx,
                             const int* __restrict__ item_idx,
                             int* __restrict__ node_map, int B, int U) {
    int t = blockIdx.x * blockDim.x + threadIdx.x;
    if (t >= 2 * B) return;
    int node = (t < B) ? user_idx[t] : (U + item_idx[t - B]);
    atomicCAS(&node_map[node], 0, t + 1);
}

// Pass 2: filtered edge scatter. One lane per edge for the filter; full-wave
// processing (ballot + shuffle broadcast) for edges whose row is needed.
__global__ void scatter_kernel(const float* __restrict__ user_emb,
                               const float* __restrict__ item_emb,
                               const float* __restrict__ vals,
                               const int* __restrict__ rows,
                               const int* __restrict__ cols,
                               const int* __restrict__ node_map,
                               float* __restrict__ comp,
                               int nnz, int U) {
    int e = blockIdx.x * blockDim.x + threadIdx.x;
    int lane = threadIdx.x & 63;
    int s = 0;
    int c = 0;
    float v = 0.f;
    if (e < nnz) {
        int r = rows[e];
        s = node_map[r];
        if (s != 0) { c = cols[e]; v = vals[e]; }
    }
    unsigned long long mask = __ballot(s != 0);
    while (mask) {
        int j = __ffsll(mask) - 1;
        mask &= mask - 1;
        int   cj    = __shfl(c, j);
        float vj    = __shfl(v, j);
        int   slotj = __shfl(s, j) - 1;
        const float* src = (cj < U) ? (user_emb + (size_t)cj * EMB_D)
                                    : (item_emb + (size_t)(cj - U) * EMB_D);
        float2 x = *(const float2*)(src + lane * 2);
        float* dst = comp + (size_t)slotj * EMB_D + lane * 2;
        atomicAdd(dst,     x.x * vj);
        atomicAdd(dst + 1, x.y * vj);
    }
}

// Pass 3: per-pair fused gather + dot. One wave per output element.
__global__ void final_kernel(const float* __restrict__ user_emb,
                             const float* __restrict__ item_emb,
                             const int* __restrict__ user_idx,
                             const int* __restrict__ item_idx,
                             const int* __restrict__ node_map,
                             const float* __restrict__ comp,
                             float* __restrict__ out, int B, int U) {
    int wid  = (blockIdx.x * blockDim.x + threadIdx.x) >> 6;
    int lane = threadIdx.x & 63;
    if (wid >= B) return;
    int un  = user_idx[wid];
    int inn = item_idx[wid];
    int su  = node_map[un] - 1;        // always claimed by pass 1
    int si  = node_map[U + inn] - 1;
    float2 eu = *(const float2*)(user_emb + (size_t)un * EMB_D + lane * 2);
    float2 ei = *(const float2*)(item_emb + (size_t)inn * EMB_D + lane * 2);
    float2 cu = *(const float2*)(comp + (size_t)su * EMB_D + lane * 2);
    float2 ci = *(const float2*)(comp + (size_t)si * EMB_D + lane * 2);
    float p = (eu.x + cu.x) * (ei.x + ci.x) + (eu.y + cu.y) * (ei.y + ci.y);
#pragma unroll
    for (int off = 32; off; off >>= 1) p += __shfl_down(p, off);
    if (lane == 0) out[wid] = 0.25f * p;
}

extern "C" void kernel_launch(void* const* d_in, const int* in_sizes, int n_in,
                              void* d_out, int out_size, void* d_ws, size_t ws_size,
                              hipStream_t stream) {
    const float* user_emb = (const float*)d_in[0];
    const float* item_emb = (const float*)d_in[1];
    const float* adj_vals = (const float*)d_in[2];
    const int*   adj_rows = (const int*)d_in[3];
    const int*   adj_cols = (const int*)d_in[4];
    const int*   user_idx = (const int*)d_in[5];
    const int*   item_idx = (const int*)d_in[6];
    float* out = (float*)d_out;

    int U   = in_sizes[0] / EMB_D;
    int I   = in_sizes[1] / EMB_D;
    int N   = U + I;
    int nnz = in_sizes[2];
    int B   = in_sizes[5];

    // Workspace layout: [comp: 2B x D floats][node_map: N ints]
    float* comp = (float*)d_ws;
    size_t comp_bytes = (size_t)2 * B * EMB_D * sizeof(float);
    int* node_map = (int*)((char*)d_ws + comp_bytes);

    hipMemsetAsync(d_ws, 0, comp_bytes + (size_t)N * sizeof(int), stream);

    claim_kernel<<<(2 * B + 255) / 256, 256, 0, stream>>>(user_idx, item_idx,
                                                          node_map, B, U);
    scatter_kernel<<<(nnz + 255) / 256, 256, 0, stream>>>(user_emb, item_emb,
                                                          adj_vals, adj_rows,
                                                          adj_cols, node_map,
                                                          comp, nnz, U);
    final_kernel<<<(B * 64 + 255) / 256, 256, 0, stream>>>(user_emb, item_emb,
                                                           user_idx, item_idx,
                                                           node_map, comp, out,
                                                           B, U);
}

// Round 2
// 162.542 us; speedup vs baseline: 3.8952x; 3.8952x over previous
//
#include <hip/hip_runtime.h>

#define EMB_D 128
#define SLOT_CAP 96   // max stored edges/slot; Poisson(32) => P(deg>96) ~ 1e-18

// ---------- Pass 1: claim needed nodes. map[node] = slot+1, slot in [0,2B). ----------
__global__ void claim_kernel(const int* __restrict__ user_idx,
                             const int* __restrict__ item_idx,
                             int* __restrict__ node_map, int B, int U) {
    int t = blockIdx.x * blockDim.x + threadIdx.x;
    if (t >= 2 * B) return;
    int node = (t < B) ? user_idx[t] : (U + item_idx[t - B]);
    atomicCAS(&node_map[node], 0, t + 1);
}

// ---------- Pass 2: bucket filtered edges into per-slot lists (counting-sort lite). ----------
// Overflow (deg > SLOT_CAP, ~never) falls back to direct atomic scatter into comp.
__global__ void fill_kernel(const float* __restrict__ user_emb,
                            const float* __restrict__ item_emb,
                            const float* __restrict__ vals,
                            const int* __restrict__ rows,
                            const int* __restrict__ cols,
                            const int* __restrict__ node_map,
                            int* __restrict__ deg,
                            int2* __restrict__ edge_buf,
                            float* __restrict__ comp,
                            int nnz, int U) {
    int e = blockIdx.x * blockDim.x + threadIdx.x;
    if (e >= nnz) return;
    int s = node_map[rows[e]];
    if (s == 0) return;
    int slot = s - 1;
    int pos = atomicAdd(&deg[slot], 1);
    int c = cols[e];
    float v = vals[e];
    if (pos < SLOT_CAP) {
        edge_buf[(size_t)slot * SLOT_CAP + pos] = make_int2(c, __float_as_int(v));
    } else {
        const float* src = (c < U) ? (user_emb + (size_t)c * EMB_D)
                                   : (item_emb + (size_t)(c - U) * EMB_D);
        float* dst = comp + (size_t)slot * EMB_D;
        for (int i = 0; i < EMB_D; ++i) atomicAdd(dst + i, v * src[i]);
    }
}

// ---------- Pass 3: one wave per slot, register accumulation, no atomics. ----------
__global__ void gather_kernel(const float* __restrict__ user_emb,
                              const float* __restrict__ item_emb,
                              const int2* __restrict__ edge_buf,
                              const int* __restrict__ deg,
                              float* __restrict__ comp,
                              int nslots, int U) {
    int wid  = (blockIdx.x * blockDim.x + threadIdx.x) >> 6;
    int lane = threadIdx.x & 63;
    if (wid >= nslots) return;
    int d = deg[wid];
    if (d == 0) return;                 // comp row already zero from memset
    if (d > SLOT_CAP) d = SLOT_CAP;     // overflow part already atomically added
    const int2* eb = edge_buf + (size_t)wid * SLOT_CAP;
    float2 acc = make_float2(0.f, 0.f);
    for (int j = 0; j < d; ++j) {
        int2 ed = eb[j];                // same addr across lanes -> broadcast
        int   c = ed.x;
        float v = __int_as_float(ed.y);
        const float* src = (c < U) ? (user_emb + (size_t)c * EMB_D)
                                   : (item_emb + (size_t)(c - U) * EMB_D);
        float2 x = *(const float2*)(src + lane * 2);
        acc.x = fmaf(v, x.x, acc.x);
        acc.y = fmaf(v, x.y, acc.y);
    }
    float* dst = comp + (size_t)wid * EMB_D + lane * 2;
    dst[0] += acc.x;                    // preserve rare overflow atomics
    dst[1] += acc.y;
}

// ---------- Pass 4: per-pair fused gather + dot. One wave per output. ----------
__global__ void final_kernel(const float* __restrict__ user_emb,
                             const float* __restrict__ item_emb,
                             const int* __restrict__ user_idx,
                             const int* __restrict__ item_idx,
                             const int* __restrict__ node_map,
                             const float* __restrict__ comp,
                             float* __restrict__ out, int B, int U) {
    int wid  = (blockIdx.x * blockDim.x + threadIdx.x) >> 6;
    int lane = threadIdx.x & 63;
    if (wid >= B) return;
    int un  = user_idx[wid];
    int inn = item_idx[wid];
    int su  = node_map[un] - 1;
    int si  = node_map[U + inn] - 1;
    float2 eu = *(const float2*)(user_emb + (size_t)un * EMB_D + lane * 2);
    float2 ei = *(const float2*)(item_emb + (size_t)inn * EMB_D + lane * 2);
    float2 cu = *(const float2*)(comp + (size_t)su * EMB_D + lane * 2);
    float2 ci = *(const float2*)(comp + (size_t)si * EMB_D + lane * 2);
    float p = (eu.x + cu.x) * (ei.x + ci.x) + (eu.y + cu.y) * (ei.y + ci.y);
#pragma unroll
    for (int off = 32; off; off >>= 1) p += __shfl_down(p, off);
    if (lane == 0) out[wid] = 0.25f * p;
}

// ---------- Fallback (ws too small): round-1 direct atomic scatter ----------
__global__ void scatter_kernel(const float* __restrict__ user_emb,
                               const float* __restrict__ item_emb,
                               const float* __restrict__ vals,
                               const int* __restrict__ rows,
                               const int* __restrict__ cols,
                               const int* __restrict__ node_map,
                               float* __restrict__ comp,
                               int nnz, int U) {
    int e = blockIdx.x * blockDim.x + threadIdx.x;
    int lane = threadIdx.x & 63;
    int s = 0; int c = 0; float v = 0.f;
    if (e < nnz) {
        int r = rows[e];
        s = node_map[r];
        if (s != 0) { c = cols[e]; v = vals[e]; }
    }
    unsigned long long mask = __ballot(s != 0);
    while (mask) {
        int j = __ffsll(mask) - 1;
        mask &= mask - 1;
        int   cj    = __shfl(c, j);
        float vj    = __shfl(v, j);
        int   slotj = __shfl(s, j) - 1;
        const float* src = (cj < U) ? (user_emb + (size_t)cj * EMB_D)
                                    : (item_emb + (size_t)(cj - U) * EMB_D);
        float2 x = *(const float2*)(src + lane * 2);
        float* dst = comp + (size_t)slotj * EMB_D + lane * 2;
        atomicAdd(dst,     x.x * vj);
        atomicAdd(dst + 1, x.y * vj);
    }
}

extern "C" void kernel_launch(void* const* d_in, const int* in_sizes, int n_in,
                              void* d_out, int out_size, void* d_ws, size_t ws_size,
                              hipStream_t stream) {
    const float* user_emb = (const float*)d_in[0];
    const float* item_emb = (const float*)d_in[1];
    const float* adj_vals = (const float*)d_in[2];
    const int*   adj_rows = (const int*)d_in[3];
    const int*   adj_cols = (const int*)d_in[4];
    const int*   user_idx = (const int*)d_in[5];
    const int*   item_idx = (const int*)d_in[6];
    float* out = (float*)d_out;

    int U   = in_sizes[0] / EMB_D;
    int I   = in_sizes[1] / EMB_D;
    int N   = U + I;
    int nnz = in_sizes[2];
    int B   = in_sizes[5];
    int S   = 2 * B;                       // slot count

    // Workspace layout: [comp S*D f32][node_map N i32][deg S i32][edge_buf S*CAP int2]
    size_t comp_bytes = (size_t)S * EMB_D * sizeof(float);
    size_t map_bytes  = ((size_t)N * sizeof(int) + 15) & ~(size_t)15;
    size_t deg_bytes  = (size_t)S * sizeof(int);
    size_t edge_bytes = (size_t)S * SLOT_CAP * sizeof(int2);

    float* comp     = (float*)d_ws;
    int*   node_map = (int*)((char*)d_ws + comp_bytes);
    int*   deg      = (int*)((char*)d_ws + comp_bytes + map_bytes);
    int2*  edge_buf = (int2*)((char*)d_ws + comp_bytes + map_bytes + deg_bytes);

    if (ws_size >= comp_bytes + map_bytes + deg_bytes + edge_bytes) {
        hipMemsetAsync(d_ws, 0, comp_bytes + map_bytes + deg_bytes, stream);
        claim_kernel<<<(S + 255) / 256, 256, 0, stream>>>(user_idx, item_idx,
                                                          node_map, B, U);
        fill_kernel<<<(nnz + 255) / 256, 256, 0, stream>>>(user_emb, item_emb,
                                                           adj_vals, adj_rows,
                                                           adj_cols, node_map,
                                                           deg, edge_buf, comp,
                                                           nnz, U);
        gather_kernel<<<(S * 64 + 255) / 256, 256, 0, stream>>>(user_emb, item_emb,
                                                                edge_buf, deg, comp,
                                                                S, U);
    } else {
        hipMemsetAsync(d_ws, 0, comp_bytes + map_bytes, stream);
        claim_kernel<<<(S + 255) / 256, 256, 0, stream>>>(user_idx, item_idx,
                                                          node_map, B, U);
        scatter_kernel<<<(nnz + 255) / 256, 256, 0, stream>>>(user_emb, item_emb,
                                                              adj_vals, adj_rows,
                                                              adj_cols, node_map,
                                                              comp, nnz, U);
    }
    final_kernel<<<(B * 64 + 255) / 256, 256, 0, stream>>>(user_emb, item_emb,
                                                           user_idx, item_idx,
                                                           node_map, comp, out,
                                                           B, U);
}

// Round 3
// 131.572 us; speedup vs baseline: 4.8120x; 1.2354x over previous
//
#include <hip/hip_runtime.h>

#define EMB_D 128
#define SLOT_CAP 96   // max stored edges/slot; max observed degree ~Poisson(32), max≈60

// ---------- Pass 1: claim needed nodes. map[node] = slot+1, slot in [0,2B). ----------
__global__ void claim_kernel(const int* __restrict__ user_idx,
                             const int* __restrict__ item_idx,
                             int* __restrict__ node_map, int B, int U) {
    int t = blockIdx.x * blockDim.x + threadIdx.x;
    if (t >= 2 * B) return;
    int node = (t < B) ? user_idx[t] : (U + item_idx[t - B]);
    atomicCAS(&node_map[node], 0, t + 1);
}

// ---------- Pass 2: bucket filtered edges into per-slot lists. ----------
// Overflow (deg > SLOT_CAP, ~never) falls back to direct atomic scatter into comp
// (comp is zeroed before this kernel, so the atomics are correct).
__global__ void fill_kernel(const float* __restrict__ user_emb,
                            const float* __restrict__ item_emb,
                            const float* __restrict__ vals,
                            const int* __restrict__ rows,
                            const int* __restrict__ cols,
                            const int* __restrict__ node_map,
                            int* __restrict__ deg,
                            int2* __restrict__ edge_buf,
                            float* __restrict__ comp,
                            int nnz, int U) {
    int e = blockIdx.x * blockDim.x + threadIdx.x;
    if (e >= nnz) return;
    int s = node_map[rows[e]];
    if (s == 0) return;
    int slot = s - 1;
    int pos = atomicAdd(&deg[slot], 1);
    int c = cols[e];
    float v = vals[e];
    if (pos < SLOT_CAP) {
        edge_buf[(size_t)slot * SLOT_CAP + pos] = make_int2(c, __float_as_int(v));
    } else {
        const float* src = (c < U) ? (user_emb + (size_t)c * EMB_D)
                                   : (item_emb + (size_t)(c - U) * EMB_D);
        float* dst = comp + (size_t)slot * EMB_D;
        for (int i = 0; i < EMB_D; ++i) atomicAdd(dst + i, v * src[i]);
    }
}

// ---------- Pass 3: one wave per slot, 4 gathers in flight, register accumulate. ----------
__global__ void gather_kernel(const float* __restrict__ user_emb,
                              const float* __restrict__ item_emb,
                              const int2* __restrict__ edge_buf,
                              const int* __restrict__ deg,
                              float* __restrict__ comp,
                              int nslots, int U) {
    int wid  = (blockIdx.x * blockDim.x + threadIdx.x) >> 6;
    int lane = threadIdx.x & 63;
    if (wid >= nslots) return;
    int d = deg[wid];
    float* dst = comp + (size_t)wid * EMB_D + lane * 2;
    bool ovf = (d > SLOT_CAP);
    int dc = ovf ? SLOT_CAP : d;
    const int2* eb = edge_buf + (size_t)wid * SLOT_CAP;
    float2 a0 = {0.f, 0.f}, a1 = {0.f, 0.f}, a2 = {0.f, 0.f}, a3 = {0.f, 0.f};
    for (int j = 0; j < dc; j += 4) {
        // SLOT_CAP is a multiple of 4 and fully allocated -> these reads are in-bounds.
        int4 q0 = *(const int4*)(eb + j);        // edges j, j+1
        int4 q1 = *(const int4*)(eb + j + 2);    // edges j+2, j+3
        int c0 = q0.x;
        int c1 = (j + 1 < dc) ? q0.z : c0;       // clamp col to a valid edge,
        int c2 = (j + 2 < dc) ? q1.x : c0;       // zero the weight for tail lanes
        int c3 = (j + 3 < dc) ? q1.z : c0;
        float v0 = __int_as_float(q0.y);
        float v1 = (j + 1 < dc) ? __int_as_float(q0.w) : 0.f;
        float v2 = (j + 2 < dc) ? __int_as_float(q1.y) : 0.f;
        float v3 = (j + 3 < dc) ? __int_as_float(q1.w) : 0.f;
        const float* s0 = (c0 < U) ? (user_emb + (size_t)c0 * EMB_D)
                                   : (item_emb + (size_t)(c0 - U) * EMB_D);
        const float* s1 = (c1 < U) ? (user_emb + (size_t)c1 * EMB_D)
                                   : (item_emb + (size_t)(c1 - U) * EMB_D);
        const float* s2 = (c2 < U) ? (user_emb + (size_t)c2 * EMB_D)
                                   : (item_emb + (size_t)(c2 - U) * EMB_D);
        const float* s3 = (c3 < U) ? (user_emb + (size_t)c3 * EMB_D)
                                   : (item_emb + (size_t)(c3 - U) * EMB_D);
        float2 x0 = *(const float2*)(s0 + lane * 2);
        float2 x1 = *(const float2*)(s1 + lane * 2);
        float2 x2 = *(const float2*)(s2 + lane * 2);
        float2 x3 = *(const float2*)(s3 + lane * 2);
        a0.x = fmaf(v0, x0.x, a0.x); a0.y = fmaf(v0, x0.y, a0.y);
        a1.x = fmaf(v1, x1.x, a1.x); a1.y = fmaf(v1, x1.y, a1.y);
        a2.x = fmaf(v2, x2.x, a2.x); a2.y = fmaf(v2, x2.y, a2.y);
        a3.x = fmaf(v3, x3.x, a3.x); a3.y = fmaf(v3, x3.y, a3.y);
    }
    float rx = (a0.x + a1.x) + (a2.x + a3.x);
    float ry = (a0.y + a1.y) + (a2.y + a3.y);
    if (ovf) { dst[0] += rx; dst[1] += ry; }   // overflow part already atomically added
    else     { dst[0] = rx;  dst[1] = ry; }    // includes d==0 -> store zeros
}

// ---------- Pass 4: per-pair fused gather + dot. One wave per output. ----------
__global__ void final_kernel(const float* __restrict__ user_emb,
                             const float* __restrict__ item_emb,
                             const int* __restrict__ user_idx,
                             const int* __restrict__ item_idx,
                             const int* __restrict__ node_map,
                             const float* __restrict__ comp,
                             float* __restrict__ out, int B, int U) {
    int wid  = (blockIdx.x * blockDim.x + threadIdx.x) >> 6;
    int lane = threadIdx.x & 63;
    if (wid >= B) return;
    int un  = user_idx[wid];
    int inn = item_idx[wid];
    int su  = node_map[un] - 1;
    int si  = node_map[U + inn] - 1;
    float2 eu = *(const float2*)(user_emb + (size_t)un * EMB_D + lane * 2);
    float2 ei = *(const float2*)(item_emb + (size_t)inn * EMB_D + lane * 2);
    float2 cu = *(const float2*)(comp + (size_t)su * EMB_D + lane * 2);
    float2 ci = *(const float2*)(comp + (size_t)si * EMB_D + lane * 2);
    float p = (eu.x + cu.x) * (ei.x + ci.x) + (eu.y + cu.y) * (ei.y + ci.y);
#pragma unroll
    for (int off = 32; off; off >>= 1) p += __shfl_down(p, off);
    if (lane == 0) out[wid] = 0.25f * p;
}

// ---------- Fallback (ws too small): direct atomic scatter ----------
__global__ void scatter_kernel(const float* __restrict__ user_emb,
                               const float* __restrict__ item_emb,
                               const float* __restrict__ vals,
                               const int* __restrict__ rows,
                               const int* __restrict__ cols,
                               const int* __restrict__ node_map,
                               float* __restrict__ comp,
                               int nnz, int U) {
    int e = blockIdx.x * blockDim.x + threadIdx.x;
    int lane = threadIdx.x & 63;
    int s = 0; int c = 0; float v = 0.f;
    if (e < nnz) {
        int r = rows[e];
        s = node_map[r];
        if (s != 0) { c = cols[e]; v = vals[e]; }
    }
    unsigned long long mask = __ballot(s != 0);
    while (mask) {
        int j = __ffsll(mask) - 1;
        mask &= mask - 1;
        int   cj    = __shfl(c, j);
        float vj    = __shfl(v, j);
        int   slotj = __shfl(s, j) - 1;
        const float* src = (cj < U) ? (user_emb + (size_t)cj * EMB_D)
                                    : (item_emb + (size_t)(cj - U) * EMB_D);
        float2 x = *(const float2*)(src + lane * 2);
        float* dst = comp + (size_t)slotj * EMB_D + lane * 2;
        atomicAdd(dst,     x.x * vj);
        atomicAdd(dst + 1, x.y * vj);
    }
}

extern "C" void kernel_launch(void* const* d_in, const int* in_sizes, int n_in,
                              void* d_out, int out_size, void* d_ws, size_t ws_size,
                              hipStream_t stream) {
    const float* user_emb = (const float*)d_in[0];
    const float* item_emb = (const float*)d_in[1];
    const float* adj_vals = (const float*)d_in[2];
    const int*   adj_rows = (const int*)d_in[3];
    const int*   adj_cols = (const int*)d_in[4];
    const int*   user_idx = (const int*)d_in[5];
    const int*   item_idx = (const int*)d_in[6];
    float* out = (float*)d_out;

    int U   = in_sizes[0] / EMB_D;
    int I   = in_sizes[1] / EMB_D;
    int N   = U + I;
    int nnz = in_sizes[2];
    int B   = in_sizes[5];
    int S   = 2 * B;                       // slot count

    // Workspace layout: [comp S*D f32][node_map N i32][deg S i32][edge_buf S*CAP int2]
    size_t comp_bytes = (size_t)S * EMB_D * sizeof(float);
    size_t map_bytes  = ((size_t)N * sizeof(int) + 15) & ~(size_t)15;
    size_t deg_bytes  = (size_t)S * sizeof(int);
    size_t edge_bytes = (size_t)S * SLOT_CAP * sizeof(int2);

    float* comp     = (float*)d_ws;
    int*   node_map = (int*)((char*)d_ws + comp_bytes);
    int*   deg      = (int*)((char*)d_ws + comp_bytes + map_bytes);
    int2*  edge_buf = (int2*)((char*)d_ws + comp_bytes + map_bytes + deg_bytes);

    if (ws_size >= comp_bytes + map_bytes + deg_bytes + edge_bytes) {
        // comp must be zero for the (theoretical) overflow atomic path in fill.
        hipMemsetAsync(d_ws, 0, comp_bytes + map_bytes + deg_bytes, stream);
        claim_kernel<<<(S + 255) / 256, 256, 0, stream>>>(user_idx, item_idx,
                                                          node_map, B, U);
        fill_kernel<<<(nnz + 255) / 256, 256, 0, stream>>>(user_emb, item_emb,
                                                           adj_vals, adj_rows,
                                                           adj_cols, node_map,
                                                           deg, edge_buf, comp,
                                                           nnz, U);
        gather_kernel<<<(S * 64 + 255) / 256, 256, 0, stream>>>(user_emb, item_emb,
                                                                edge_buf, deg, comp,
                                                                S, U);
    } else {
        hipMemsetAsync(d_ws, 0, comp_bytes + map_bytes, stream);
        claim_kernel<<<(S + 255) / 256, 256, 0, stream>>>(user_idx, item_idx,
                                                          node_map, B, U);
        scatter_kernel<<<(nnz + 255) / 256, 256, 0, stream>>>(user_emb, item_emb,
                                                              adj_vals, adj_rows,
                                                              adj_cols, node_map,
                                                              comp, nnz, U);
    }
    final_kernel<<<(B * 64 + 255) / 256, 256, 0, stream>>>(user_emb, item_emb,
                                                           user_idx, item_idx,
                                                           node_map, comp, out,
                                                           B, U);
}